// Round 12
// baseline (209.304 us; speedup 1.0000x reference)
//
#include <hip/hip_runtime.h>
#include <hip/hip_bf16.h>
#include <hip/hip_fp16.h>
#include <math.h>

// Problem constants (fixed by reference)
#define N_NODES 4096
#define N_SUBS  1024
#define NFEAT   128
#define HIDDEN  512
#define NHEADS  8
#define DHEAD   64
#define CAP     128   // max neighbors/row (mean ~42, sd ~6.4; 128 = +13 sigma)
#define ROWG    4     // neighbor groups in fp32 gat_agg phase B
#define HGS     8     // neighbor groups in fp16 gat_agg phase B

// native clang vector (accepted by __builtin_nontemporal_load, unlike float4)
typedef float vfloat4 __attribute__((ext_vector_type(4)));

// 16-byte packet of 8 halves
struct alignas(16) h8 { __half2 a, b, c, d; };

// ---------------------------------------------------------------------------
// PHASE 1 mega-dispatch: independent jobs co-scheduled so the Wpart GEMM
// hides under the 68 MB adjacency stream.
//   blocks [0, 1280)        : ballot edge extraction (node + sub graphs)
//   blocks [1280, 1280+384) : Wpart split-K GEMM lin_w@node_W1 + bias slab
// ---------------------------------------------------------------------------
#define NB_EXTRACT (N_NODES / 4 + N_SUBS / 4)      // 1280
#define NB_GEMM    (8 * 3 * 16)                    // 384
#define BM 64
#define BN 64
#define BK 16

__global__ __launch_bounds__(256) void phase1(const float* __restrict__ adj_n,
                                              const float* __restrict__ adj_s,
                                              int* __restrict__ cnt_n,
                                              int* __restrict__ nbr_n,
                                              int* __restrict__ cnt_s,
                                              int* __restrict__ nbr_s,
                                              const float* __restrict__ lin_w,
                                              const float* __restrict__ node_W1,
                                              const float* __restrict__ lin_b,
                                              float* __restrict__ Wpart,
                                              float* __restrict__ bpart) {
    const int tid = threadIdx.x;
    if (blockIdx.x < NB_EXTRACT) {
        // ---- edge extraction ----
        const int w = tid >> 6;
        const int lane = tid & 63;
        const float* adj;
        int N, row;
        int* cnt;
        int* nbr;
        if (blockIdx.x < N_NODES / 4) {
            adj = adj_n; N = N_NODES; cnt = cnt_n; nbr = nbr_n;
            row = blockIdx.x * 4 + w;
        } else {
            adj = adj_s; N = N_SUBS; cnt = cnt_s; nbr = nbr_s;
            row = (blockIdx.x - N_NODES / 4) * 4 + w;
        }
        const vfloat4* rowp = (const vfloat4*)(adj + (size_t)row * N);
        int* nrow = nbr + (row << 7);
        const int n4 = N >> 2;
        int c = 0;
        const unsigned long long below = (1ull << lane) - 1ull;
        for (int c4 = lane; c4 < n4; c4 += 64) {
            const vfloat4 v = __builtin_nontemporal_load(&rowp[c4]);
            const int col = c4 << 2;
            unsigned long long m;
            bool p;
            p = v.x > 0.0f; m = __ballot(p);
            if (p) { int q = c + __popcll(m & below); if (q < CAP) nrow[q] = col; }
            c += __popcll(m);
            p = v.y > 0.0f; m = __ballot(p);
            if (p) { int q = c + __popcll(m & below); if (q < CAP) nrow[q] = col + 1; }
            c += __popcll(m);
            p = v.z > 0.0f; m = __ballot(p);
            if (p) { int q = c + __popcll(m & below); if (q < CAP) nrow[q] = col + 2; }
            c += __popcll(m);
            p = v.w > 0.0f; m = __ballot(p);
            if (p) { int q = c + __popcll(m & below); if (q < CAP) nrow[q] = col + 3; }
            c += __popcll(m);
        }
        if (lane == 0) cnt[row] = c < CAP ? c : CAP;
        return;
    }
    {
        // ---- Wpart split-K GEMM: lin_w[128,512] @ node_W1[512,512] ----
        const int b = blockIdx.x - NB_EXTRACT;
        const int bn = (b & 7) * BN;
        const int rem = b >> 3;
        const int by = rem % 3;        // 0,1 = GEMM bm slab; 2 = bias slab
        const int bz = rem / 3;        // 0..15
        const int M = NFEAT, N = HIDDEN, K = HIDDEN;
        const int k_chunk = K / 16;    // 32
        const int k_start = bz * k_chunk;
        __shared__ float As[BK][BM + 4];
        __shared__ float Bs[BK][BN + 4];
        if (by == 2) {
            const int q = tid >> 6;
            const int n = tid & 63;
            const int sub = k_chunk >> 2;          // 8
            const int kb = k_start + q * sub;
            float s = 0.0f;
            for (int k = 0; k < sub; k++)
                s += lin_b[kb + k] * node_W1[(size_t)(kb + k) * N + bn + n];
            float* red = (float*)As;
            red[q * 64 + n] = s;
            __syncthreads();
            if (q == 0)
                bpart[bz * N + bn + n] = red[n] + red[64 + n] + red[128 + n] + red[192 + n];
            return;
        }
        const int bm = by * BM;
        float* Cw = Wpart + (size_t)bz * M * N;
        const int tr = tid >> 4;
        const int tc = tid & 15;
        const int am = tid >> 2;
        const int ak4 = (tid & 3) * 4;
        const int bk = tid >> 4;
        const int bn0 = (tid & 15) * 4;
        float acc[4][4] = {};
        for (int k0 = k_start; k0 < k_start + k_chunk; k0 += BK) {
            const float4 va = *(const float4*)&lin_w[(size_t)(bm + am) * K + k0 + ak4];
            const float4 vb = *(const float4*)&node_W1[(size_t)(k0 + bk) * N + bn + bn0];
            As[ak4 + 0][am] = va.x;
            As[ak4 + 1][am] = va.y;
            As[ak4 + 2][am] = va.z;
            As[ak4 + 3][am] = va.w;
            *(float4*)&Bs[bk][bn0] = vb;
            __syncthreads();
#pragma unroll
            for (int k = 0; k < BK; k++) {
                const float4 a4 = *(const float4*)&As[k][tr * 4];
                const float4 b4 = *(const float4*)&Bs[k][tc * 4];
                const float a[4] = {a4.x, a4.y, a4.z, a4.w};
                const float bb[4] = {b4.x, b4.y, b4.z, b4.w};
#pragma unroll
                for (int i = 0; i < 4; i++)
#pragma unroll
                    for (int j = 0; j < 4; j++)
                        acc[i][j] += a[i] * bb[j];
            }
            __syncthreads();
        }
#pragma unroll
        for (int i = 0; i < 4; i++) {
            const int m = bm + tr * 4 + i;
            float4 o = {acc[i][0], acc[i][1], acc[i][2], acc[i][3]};
            *(float4*)&Cw[(size_t)m * N + bn + tc * 4] = o;
        }
    }
}

// ---------------------------------------------------------------------------
// fp32 tiled GEMM: BM=BN=64, BK=16, 4x4/thread. blockIdx.z = split-K chunk.
// Optional: fused attention-logit epilogue (asrc, gridDim.z==1), fp16 C
// output (C_h != nullptr -> write half, skip fp32 C store).
// ---------------------------------------------------------------------------
__global__ __launch_bounds__(256) void gemm_f32(const float* __restrict__ A,
                                                const float* __restrict__ B,
                                                const float* __restrict__ bias,
                                                float* __restrict__ C,
                                                int M, int N, int K, int k_chunk,
                                                const float* __restrict__ asrc,
                                                const float* __restrict__ adst,
                                                float* __restrict__ fs,
                                                float* __restrict__ fd,
                                                __half* __restrict__ C_h) {
    __shared__ float As[BK][BM + 4];
    __shared__ float Bs[BK][BN + 4];
    const int tid = threadIdx.x;
    const int bm = blockIdx.y * BM;
    const int bn = blockIdx.x * BN;
    const int k_start = blockIdx.z * k_chunk;
    const int k_end = (k_start + k_chunk) < K ? (k_start + k_chunk) : K;
    float* Cw = C + (size_t)blockIdx.z * M * N;
    const int tr = tid >> 4;
    const int tc = tid & 15;
    const int am = tid >> 2;
    const int ak4 = (tid & 3) * 4;
    const int bk = tid >> 4;
    const int bn0 = (tid & 15) * 4;
    float acc[4][4] = {};
    for (int k0 = k_start; k0 < k_end; k0 += BK) {
        const float4 va = *(const float4*)&A[(size_t)(bm + am) * K + k0 + ak4];
        const float4 vb = *(const float4*)&B[(size_t)(k0 + bk) * N + bn + bn0];
        As[ak4 + 0][am] = va.x;
        As[ak4 + 1][am] = va.y;
        As[ak4 + 2][am] = va.z;
        As[ak4 + 3][am] = va.w;
        *(float4*)&Bs[bk][bn0] = vb;
        __syncthreads();
#pragma unroll
        for (int k = 0; k < BK; k++) {
            const float4 a4 = *(const float4*)&As[k][tr * 4];
            const float4 b4 = *(const float4*)&Bs[k][tc * 4];
            const float a[4] = {a4.x, a4.y, a4.z, a4.w};
            const float b[4] = {b4.x, b4.y, b4.z, b4.w};
#pragma unroll
            for (int i = 0; i < 4; i++)
#pragma unroll
                for (int j = 0; j < 4; j++)
                    acc[i][j] += a[i] * b[j];
        }
        __syncthreads();
    }
#pragma unroll
    for (int i = 0; i < 4; i++) {
        const int m = bm + tr * 4 + i;
        if (bias) {
            const float4 bv = *(const float4*)&bias[bn + tc * 4];
            acc[i][0] += bv.x; acc[i][1] += bv.y; acc[i][2] += bv.z; acc[i][3] += bv.w;
        }
        if (C_h) {
            __half2 p0 = __floats2half2_rn(acc[i][0], acc[i][1]);
            __half2 p1 = __floats2half2_rn(acc[i][2], acc[i][3]);
            __half2* hp = (__half2*)&C_h[(size_t)m * N + bn + tc * 4];
            hp[0] = p0;
            hp[1] = p1;
        } else {
            float4 o = {acc[i][0], acc[i][1], acc[i][2], acc[i][3]};
            *(float4*)&Cw[(size_t)m * N + bn + tc * 4] = o;
        }
    }
    if (asrc) {
        const int h = blockIdx.x;                  // BN==DHEAD
        const float4 as4 = *(const float4*)&asrc[h * DHEAD + tc * 4];
        const float4 ad4 = *(const float4*)&adst[h * DHEAD + tc * 4];
#pragma unroll
        for (int i = 0; i < 4; i++) {
            float vs = acc[i][0] * as4.x + acc[i][1] * as4.y +
                       acc[i][2] * as4.z + acc[i][3] * as4.w;
            float vd = acc[i][0] * ad4.x + acc[i][1] * ad4.y +
                       acc[i][2] * ad4.z + acc[i][3] * ad4.w;
#pragma unroll
            for (int off = 1; off < 16; off <<= 1) {
                vs += __shfl_xor(vs, off, 64);
                vd += __shfl_xor(vd, off, 64);
            }
            if (tc == 0) {
                const int m = bm + tr * 4 + i;
                fs[h * M + m] = vs;
                fd[h * M + m] = vd;
            }
        }
    }
}

// Fused reduction of W-partials (len1, nz1) and bias-partials (len2, nz2).
__global__ __launch_bounds__(256) void reduce_both(const float* __restrict__ p1,
                                                   float* __restrict__ o1,
                                                   int len1, int nz1,
                                                   const float* __restrict__ p2,
                                                   float* __restrict__ o2,
                                                   int len2, int nz2,
                                                   int blocks1) {
    if ((int)blockIdx.x < blocks1) {
        const int i = blockIdx.x * 256 + threadIdx.x;
        if (i < len1) {
            float s = 0.0f;
            for (int z = 0; z < nz1; z++) s += p1[(size_t)z * len1 + i];
            o1[i] = s;
        }
    } else {
        const int i = (blockIdx.x - blocks1) * 256 + threadIdx.x;
        if (i < len2) {
            float s = 0.0f;
            for (int z = 0; z < nz2; z++) s += p2[(size_t)z * len2 + i];
            o2[i] = s;
        }
    }
}

// ---------------------------------------------------------------------------
// Fused split-K reduce + attention logits for the sub layer.
// ---------------------------------------------------------------------------
__global__ __launch_bounds__(512) void reduce_fsfd(const float* __restrict__ part,
                                                   float* __restrict__ wh,
                                                   const float* __restrict__ asrc,
                                                   const float* __restrict__ adst,
                                                   float* __restrict__ fs,
                                                   float* __restrict__ fd,
                                                   int M, int nz) {
    const int n = blockIdx.x;
    const int tid = threadIdx.x;
    float v = 0.0f;
    for (int z = 0; z < nz; z++)
        v += part[((size_t)z * M + n) * HIDDEN + tid];
    wh[(size_t)n * HIDDEN + tid] = v;
    const int h = tid >> 6;
    const int d = tid & 63;
    float vs = v * asrc[h * DHEAD + d];
    float vd = v * adst[h * DHEAD + d];
#pragma unroll
    for (int off = 32; off >= 1; off >>= 1) {
        vs += __shfl_xor(vs, off, 64);
        vd += __shfl_xor(vd, off, 64);
    }
    if (d == 0) {
        fs[h * M + n] = vs;
        fd[h * M + n] = vd;
    }
}

// ---------------------------------------------------------------------------
// Shared softmax phase (device fn). Normalized alpha left in ex[][].
// ---------------------------------------------------------------------------
__device__ __forceinline__ void gat_softmax(const float* __restrict__ fs,
                                            const float* __restrict__ fd,
                                            const int* snbr, float (*ex)[CAP + 1],
                                            int C, int i, int N, int tid) {
    const int h = tid >> 6;
    const int lane = tid & 63;
    const float fsi = fs[h * N + i];
    const float* __restrict__ fdh = fd + h * N;
    float m = -1e30f;
    for (int k = lane; k < C; k += 64) {
        float e = fsi + fdh[snbr[k]];
        e = e > 0.0f ? e : 0.2f * e;
        ex[h][k] = e;
        m = fmaxf(m, e);
    }
#pragma unroll
    for (int off = 32; off >= 1; off >>= 1) m = fmaxf(m, __shfl_xor(m, off, 64));
    float ssum = 0.0f;
    for (int k = lane; k < C; k += 64) {
        float v = __expf(ex[h][k] - m);
        ex[h][k] = v;
        ssum += v;
    }
#pragma unroll
    for (int off = 32; off >= 1; off >>= 1) ssum += __shfl_xor(ssum, off, 64);
    const float inv = 1.0f / ssum;
    for (int k = lane; k < C; k += 64) ex[h][k] *= inv;
}

// ---------------------------------------------------------------------------
// Node GAT aggregate: fp16 Wh gather. Batch-load restructure: each group owns
// ~C/8 (~5-6) neighbors; ALL its loads issue back-to-back (exec-masked,
// wave-uniform guards) before any conversion — max MLP. Transposed sacc
// [g][e][lane] kills the 16-way bank conflicts (R10: 754K conflict cycles).
// ---------------------------------------------------------------------------
__global__ __launch_bounds__(512) void gat_agg_h(const __half* __restrict__ Wh,
                                                 const float* __restrict__ fs,
                                                 const float* __restrict__ fd,
                                                 const int* __restrict__ cnt,
                                                 const int* __restrict__ nbr,
                                                 float* __restrict__ out, int N) {
    __shared__ int snbr[CAP];
    __shared__ float ex[NHEADS][CAP + 1];
    __shared__ float sacc[HGS][8][64];        // [group][feat-sub][lane] 16 KB
    const int i = blockIdx.x;
    const int tid = threadIdx.x;
    int C = cnt[i];
    C = C < CAP ? C : CAP;
    for (int k = tid; k < C; k += 512) snbr[k] = nbr[(i << 7) + k];
    __syncthreads();
    gat_softmax(fs, fd, snbr, ex, C, i, N, tid);
    __syncthreads();
    const int g = tid >> 6;                   // 0..7 neighbor group
    const int t = tid & 63;                   // half8 slot within row
    const int hh = t >> 3;                    // head of this slot
    float acc[8] = {};
    for (int kb = g; kb < C; kb += 8 * HGS) {
        // batch: issue all (<=8) loads of this group's neighbors first
        h8 ww[8];
        float aa[8];
#pragma unroll
        for (int u = 0; u < 8; u++) {
            const int kk = kb + u * HGS;
            if (kk < C) {                     // wave-uniform guard
                ww[u] = *(const h8*)&Wh[(size_t)snbr[kk] * HIDDEN + 8 * t];
                aa[u] = ex[hh][kk];
            }
        }
#pragma unroll
        for (int u = 0; u < 8; u++) {
            const int kk = kb + u * HGS;
            if (kk < C) {
                float2 f;
                f = __half22float2(ww[u].a); acc[0] += aa[u] * f.x; acc[1] += aa[u] * f.y;
                f = __half22float2(ww[u].b); acc[2] += aa[u] * f.x; acc[3] += aa[u] * f.y;
                f = __half22float2(ww[u].c); acc[4] += aa[u] * f.x; acc[5] += aa[u] * f.y;
                f = __half22float2(ww[u].d); acc[6] += aa[u] * f.x; acc[7] += aa[u] * f.y;
            }
        }
    }
    if (g != 0) {
#pragma unroll
        for (int e = 0; e < 8; e++) sacc[g][e][t] = acc[e];   // conflict-free
    }
    __syncthreads();
    if (g == 0) {
#pragma unroll
        for (int e = 0; e < 8; e++) {
            float r = acc[e];
#pragma unroll
            for (int gg = 1; gg < HGS; gg++) r += sacc[gg][e][t];
            acc[e] = r > 0.0f ? r : __expf(r) - 1.0f;
        }
        float4 o0 = {acc[0], acc[1], acc[2], acc[3]};
        float4 o1 = {acc[4], acc[5], acc[6], acc[7]};
        float4* op = (float4*)&out[(size_t)i * HIDDEN + 8 * t];
        op[0] = o0;
        op[1] = o1;
    }
}

// ---------------------------------------------------------------------------
// Sub GAT aggregate: fp32 gather (feeds output directly). Transposed sacc.
// ---------------------------------------------------------------------------
__global__ __launch_bounds__(512) void gat_agg_f(const float* __restrict__ Wh,
                                                 const float* __restrict__ fs,
                                                 const float* __restrict__ fd,
                                                 const int* __restrict__ cnt,
                                                 const int* __restrict__ nbr,
                                                 float* __restrict__ out, int N) {
    __shared__ int snbr[CAP];
    __shared__ float ex[NHEADS][CAP + 1];
    __shared__ float sacc[ROWG][4][128];      // [group][feat-sub][lane] 8 KB
    const int i = blockIdx.x;
    const int tid = threadIdx.x;
    int C = cnt[i];
    C = C < CAP ? C : CAP;
    for (int k = tid; k < C; k += 512) snbr[k] = nbr[(i << 7) + k];
    __syncthreads();
    gat_softmax(fs, fd, snbr, ex, C, i, N, tid);
    __syncthreads();
    const int g = tid >> 7;                   // 0..3
    const int t = tid & 127;                  // float4 slot within row
    const int hh = t >> 4;
    float acc[4] = {};
    for (int kb = g; kb < C; kb += 8 * ROWG) {
        float4 ww[8];
        float aa[8];
#pragma unroll
        for (int u = 0; u < 8; u++) {
            const int kk = kb + u * ROWG;
            if (kk < C) {
                ww[u] = *(const float4*)&Wh[(size_t)snbr[kk] * HIDDEN + 4 * t];
                aa[u] = ex[hh][kk];
            }
        }
#pragma unroll
        for (int u = 0; u < 8; u++) {
            const int kk = kb + u * ROWG;
            if (kk < C) {
                acc[0] += aa[u] * ww[u].x;
                acc[1] += aa[u] * ww[u].y;
                acc[2] += aa[u] * ww[u].z;
                acc[3] += aa[u] * ww[u].w;
            }
        }
    }
    if (g != 0) {
#pragma unroll
        for (int e = 0; e < 4; e++) sacc[g][e][t] = acc[e];
    }
    __syncthreads();
    if (g == 0) {
#pragma unroll
        for (int e = 0; e < 4; e++) {
            float r = acc[e];
#pragma unroll
            for (int gg = 1; gg < ROWG; gg++) r += sacc[gg][e][t];
            acc[e] = r > 0.0f ? r : __expf(r) - 1.0f;
        }
        float4 o = {acc[0], acc[1], acc[2], acc[3]};
        *(float4*)&out[(size_t)i * HIDDEN + 4 * t] = o;
    }
}

// ---------------------------------------------------------------------------
// Segment-mean pooling. seg_ids sorted. One block per substation.
// ---------------------------------------------------------------------------
__global__ __launch_bounds__(512) void pool_kernel(const float* __restrict__ hin,
                                                   const int* __restrict__ seg,
                                                   float* __restrict__ sout) {
    const int s = blockIdx.x;
    const int d = threadIdx.x;
    int lo = 0, hi = N_NODES;
    while (lo < hi) { int mid = (lo + hi) >> 1; if (seg[mid] < s) lo = mid + 1; else hi = mid; }
    const int start = lo;
    hi = N_NODES;
    while (lo < hi) { int mid = (lo + hi) >> 1; if (seg[mid] < s + 1) lo = mid + 1; else hi = mid; }
    const int end = lo;
    float acc = 0.0f;
    for (int r = start; r < end; r++) acc += hin[(size_t)r * HIDDEN + d];
    const int c = end - start;
    sout[(size_t)s * HIDDEN + d] = acc / (c > 0 ? (float)c : 1.0f);
}

// ---------------------------------------------------------------------------
extern "C" void kernel_launch(void* const* d_in, const int* in_sizes, int n_in,
                              void* d_out, int out_size, void* d_ws, size_t ws_size,
                              hipStream_t stream) {
    const float* x        = (const float*)d_in[0];
    const float* adj_node = (const float*)d_in[1];
    const float* adj_sub  = (const float*)d_in[2];
    const int*   seg_ids  = (const int*)d_in[3];
    const float* lin_w    = (const float*)d_in[4];
    const float* lin_b    = (const float*)d_in[5];
    // _stacked_gats bug: every layer reads the ORIGINAL h; only the LAST
    // layer's output survives. Use layer index 1 only.
    const float* node_W1    = (const float*)d_in[6]  + HIDDEN * HIDDEN;
    const float* node_asrc1 = (const float*)d_in[7]  + NHEADS * DHEAD;
    const float* node_adst1 = (const float*)d_in[8]  + NHEADS * DHEAD;
    const float* sub_W1     = (const float*)d_in[9]  + HIDDEN * HIDDEN;
    const float* sub_asrc1  = (const float*)d_in[10] + NHEADS * DHEAD;
    const float* sub_adst1  = (const float*)d_in[11] + NHEADS * DHEAD;
    float* out = (float*)d_out;

    char* ws = (char*)d_ws;
    float* bufA  = (float*)(ws);                              // 8 MB
    float* bufB  = (float*)(ws + (size_t)8 * 1024 * 1024);    // 8 MB
    float* fs_n  = (float*)(ws + (size_t)16 * 1024 * 1024);
    float* fd_n  = fs_n + NHEADS * N_NODES;
    float* fs_s  = fd_n + NHEADS * N_NODES;
    float* fd_s  = fs_s + NHEADS * N_SUBS;
    int*   cnt_n = (int*)(fd_s + NHEADS * N_SUBS);
    int*   cnt_s = cnt_n + N_NODES;
    int*   nbr_n = cnt_s + N_SUBS;                            // 2 MB
    int*   nbr_s = nbr_n + N_NODES * CAP;                     // 512 KB

    // bufB overlays: phase-1 GEMM scratch -> gatom -> Spart
    float*  Wpart = bufB;                                     // 16*128*512 (4 MB)
    float*  Wfuse = bufB + 16 * NFEAT * HIDDEN;               // 256 KB
    float*  bpart = Wfuse + NFEAT * HIDDEN;                   // 32 KB
    float*  bias2 = bpart + 16 * HIDDEN;                      // 2 KB
    float*  gatom = bufB;                                     // 4096*512 (after gemm3)
    float*  Spart = bufB;                                     // 4*1024*512 (after pool)
    // bufA overlays: wh_n(fp16) -> sp -> wh_s
    __half* wh_n  = (__half*)bufA;                            // 4096*512 fp16 (4 MB)
    float*  sp    = bufA;                                     // 1024*512 (wh_n dead)
    float*  wh_s  = bufA + (size_t)N_SUBS * HIDDEN;           // 1024*512

    // 1. PHASE 1: edge extraction + Wpart split-K GEMM + bias slab
    phase1<<<NB_EXTRACT + NB_GEMM, 256, 0, stream>>>(
        adj_node, adj_sub, cnt_n, nbr_n, cnt_s, nbr_s,
        lin_w, node_W1, lin_b, Wpart, bpart);
    // 2. reduce W partials + bias partials -> Wfuse, bias2
    reduce_both<<<NFEAT * HIDDEN / 256 + 2, 256, 0, stream>>>(
        Wpart, Wfuse, NFEAT * HIDDEN, 16, bpart, bias2, HIDDEN, 16,
        NFEAT * HIDDEN / 256);
    // 3. wh_n(fp16) = x @ Wfuse + bias2, fused fs/fd epilogue
    gemm_f32<<<dim3(HIDDEN / BN, N_NODES / BM, 1), 256, 0, stream>>>(
        x, Wfuse, bias2, nullptr, N_NODES, HIDDEN, NFEAT, NFEAT,
        node_asrc1, node_adst1, fs_n, fd_n, wh_n);
    // 4. node GAT aggregate (fp16 batch gather) -> gatom
    gat_agg_h<<<N_NODES, 512, 0, stream>>>(wh_n, fs_n, fd_n, cnt_n, nbr_n,
                                           gatom, N_NODES);
    // 5. segment-mean pool -> sp (bufA; wh_n dead)
    pool_kernel<<<N_SUBS, 512, 0, stream>>>(gatom, seg_ids, sp);
    // 6. wh_s partials = sp @ sub_W1 (split-K=4)
    gemm_f32<<<dim3(HIDDEN / BN, N_SUBS / BM, 4), 256, 0, stream>>>(
        sp, sub_W1, nullptr, Spart, N_SUBS, HIDDEN, HIDDEN, HIDDEN / 4,
        nullptr, nullptr, nullptr, nullptr, nullptr);
    // 7. fused reduce + sub attention logits
    reduce_fsfd<<<N_SUBS, 512, 0, stream>>>(Spart, wh_s, sub_asrc1, sub_adst1,
                                            fs_s, fd_s, N_SUBS, 4);
    // 8. sub GAT aggregate (fp32) -> final output
    gat_agg_f<<<N_SUBS, 512, 0, stream>>>(wh_s, fs_s, fd_s, cnt_s, nbr_s,
                                          out, N_SUBS);
}

// Round 13
// 201.050 us; speedup vs baseline: 1.0411x; 1.0411x over previous
//
#include <hip/hip_runtime.h>
#include <hip/hip_bf16.h>
#include <hip/hip_fp16.h>
#include <math.h>

// Problem constants (fixed by reference)
#define N_NODES 4096
#define N_SUBS  1024
#define NFEAT   128
#define HIDDEN  512
#define NHEADS  8
#define DHEAD   64
#define CAP     128   // max neighbors/row (mean ~42, sd ~6.4; 128 = +13 sigma)
#define ROWG    4     // neighbor groups in fp32 gat_agg phase B
#define CAPP    (CAP + 4)   // alpha LDS pad: stride 132 -> <=2-way banks (free)

// native clang vector (accepted by __builtin_nontemporal_load, unlike float4)
typedef float vfloat4 __attribute__((ext_vector_type(4)));

// 16-byte packet of 8 halves
struct alignas(16) h8 { __half2 a, b, c, d; };

// ---------------------------------------------------------------------------
// PHASE 1 mega-dispatch: independent jobs co-scheduled so the Wpart GEMM
// hides under the 68 MB adjacency stream.
//   blocks [0, 1280)        : ballot edge extraction (node + sub graphs)
//   blocks [1280, 1280+384) : Wpart split-K GEMM lin_w@node_W1 + bias slab
// ---------------------------------------------------------------------------
#define NB_EXTRACT (N_NODES / 4 + N_SUBS / 4)      // 1280
#define NB_GEMM    (8 * 3 * 16)                    // 384
#define BM 64
#define BN 64
#define BK 16

__global__ __launch_bounds__(256) void phase1(const float* __restrict__ adj_n,
                                              const float* __restrict__ adj_s,
                                              int* __restrict__ cnt_n,
                                              int* __restrict__ nbr_n,
                                              int* __restrict__ cnt_s,
                                              int* __restrict__ nbr_s,
                                              const float* __restrict__ lin_w,
                                              const float* __restrict__ node_W1,
                                              const float* __restrict__ lin_b,
                                              float* __restrict__ Wpart,
                                              float* __restrict__ bpart) {
    const int tid = threadIdx.x;
    if (blockIdx.x < NB_EXTRACT) {
        // ---- edge extraction ----
        const int w = tid >> 6;
        const int lane = tid & 63;
        const float* adj;
        int N, row;
        int* cnt;
        int* nbr;
        if (blockIdx.x < N_NODES / 4) {
            adj = adj_n; N = N_NODES; cnt = cnt_n; nbr = nbr_n;
            row = blockIdx.x * 4 + w;
        } else {
            adj = adj_s; N = N_SUBS; cnt = cnt_s; nbr = nbr_s;
            row = (blockIdx.x - N_NODES / 4) * 4 + w;
        }
        const vfloat4* rowp = (const vfloat4*)(adj + (size_t)row * N);
        int* nrow = nbr + (row << 7);
        const int n4 = N >> 2;
        int c = 0;
        const unsigned long long below = (1ull << lane) - 1ull;
        for (int c4 = lane; c4 < n4; c4 += 64) {
            const vfloat4 v = __builtin_nontemporal_load(&rowp[c4]);
            const int col = c4 << 2;
            unsigned long long m;
            bool p;
            p = v.x > 0.0f; m = __ballot(p);
            if (p) { int q = c + __popcll(m & below); if (q < CAP) nrow[q] = col; }
            c += __popcll(m);
            p = v.y > 0.0f; m = __ballot(p);
            if (p) { int q = c + __popcll(m & below); if (q < CAP) nrow[q] = col + 1; }
            c += __popcll(m);
            p = v.z > 0.0f; m = __ballot(p);
            if (p) { int q = c + __popcll(m & below); if (q < CAP) nrow[q] = col + 2; }
            c += __popcll(m);
            p = v.w > 0.0f; m = __ballot(p);
            if (p) { int q = c + __popcll(m & below); if (q < CAP) nrow[q] = col + 3; }
            c += __popcll(m);
        }
        if (lane == 0) cnt[row] = c < CAP ? c : CAP;
        return;
    }
    {
        // ---- Wpart split-K GEMM: lin_w[128,512] @ node_W1[512,512] ----
        const int b = blockIdx.x - NB_EXTRACT;
        const int bn = (b & 7) * BN;
        const int rem = b >> 3;
        const int by = rem % 3;        // 0,1 = GEMM bm slab; 2 = bias slab
        const int bz = rem / 3;        // 0..15
        const int M = NFEAT, N = HIDDEN, K = HIDDEN;
        const int k_chunk = K / 16;    // 32
        const int k_start = bz * k_chunk;
        __shared__ float As[BK][BM + 4];
        __shared__ float Bs[BK][BN + 4];
        if (by == 2) {
            const int q = tid >> 6;
            const int n = tid & 63;
            const int sub = k_chunk >> 2;          // 8
            const int kb = k_start + q * sub;
            float s = 0.0f;
            for (int k = 0; k < sub; k++)
                s += lin_b[kb + k] * node_W1[(size_t)(kb + k) * N + bn + n];
            float* red = (float*)As;
            red[q * 64 + n] = s;
            __syncthreads();
            if (q == 0)
                bpart[bz * N + bn + n] = red[n] + red[64 + n] + red[128 + n] + red[192 + n];
            return;
        }
        const int bm = by * BM;
        float* Cw = Wpart + (size_t)bz * M * N;
        const int tr = tid >> 4;
        const int tc = tid & 15;
        const int am = tid >> 2;
        const int ak4 = (tid & 3) * 4;
        const int bk = tid >> 4;
        const int bn0 = (tid & 15) * 4;
        float acc[4][4] = {};
        for (int k0 = k_start; k0 < k_start + k_chunk; k0 += BK) {
            const float4 va = *(const float4*)&lin_w[(size_t)(bm + am) * K + k0 + ak4];
            const float4 vb = *(const float4*)&node_W1[(size_t)(k0 + bk) * N + bn + bn0];
            As[ak4 + 0][am] = va.x;
            As[ak4 + 1][am] = va.y;
            As[ak4 + 2][am] = va.z;
            As[ak4 + 3][am] = va.w;
            *(float4*)&Bs[bk][bn0] = vb;
            __syncthreads();
#pragma unroll
            for (int k = 0; k < BK; k++) {
                const float4 a4 = *(const float4*)&As[k][tr * 4];
                const float4 b4 = *(const float4*)&Bs[k][tc * 4];
                const float a[4] = {a4.x, a4.y, a4.z, a4.w};
                const float bb[4] = {b4.x, b4.y, b4.z, b4.w};
#pragma unroll
                for (int i = 0; i < 4; i++)
#pragma unroll
                    for (int j = 0; j < 4; j++)
                        acc[i][j] += a[i] * bb[j];
            }
            __syncthreads();
        }
#pragma unroll
        for (int i = 0; i < 4; i++) {
            const int m = bm + tr * 4 + i;
            float4 o = {acc[i][0], acc[i][1], acc[i][2], acc[i][3]};
            *(float4*)&Cw[(size_t)m * N + bn + tc * 4] = o;
        }
    }
}

// ---------------------------------------------------------------------------
// fp32 tiled GEMM: BM=BN=64, BK=16, 4x4/thread. blockIdx.z = split-K chunk.
// Optional: fused attention-logit epilogue (asrc, gridDim.z==1), fp16 C
// output (C_h != nullptr -> write half, skip fp32 C store).
// ---------------------------------------------------------------------------
__global__ __launch_bounds__(256) void gemm_f32(const float* __restrict__ A,
                                                const float* __restrict__ B,
                                                const float* __restrict__ bias,
                                                float* __restrict__ C,
                                                int M, int N, int K, int k_chunk,
                                                const float* __restrict__ asrc,
                                                const float* __restrict__ adst,
                                                float* __restrict__ fs,
                                                float* __restrict__ fd,
                                                __half* __restrict__ C_h) {
    __shared__ float As[BK][BM + 4];
    __shared__ float Bs[BK][BN + 4];
    const int tid = threadIdx.x;
    const int bm = blockIdx.y * BM;
    const int bn = blockIdx.x * BN;
    const int k_start = blockIdx.z * k_chunk;
    const int k_end = (k_start + k_chunk) < K ? (k_start + k_chunk) : K;
    float* Cw = C + (size_t)blockIdx.z * M * N;
    const int tr = tid >> 4;
    const int tc = tid & 15;
    const int am = tid >> 2;
    const int ak4 = (tid & 3) * 4;
    const int bk = tid >> 4;
    const int bn0 = (tid & 15) * 4;
    float acc[4][4] = {};
    for (int k0 = k_start; k0 < k_end; k0 += BK) {
        const float4 va = *(const float4*)&A[(size_t)(bm + am) * K + k0 + ak4];
        const float4 vb = *(const float4*)&B[(size_t)(k0 + bk) * N + bn + bn0];
        As[ak4 + 0][am] = va.x;
        As[ak4 + 1][am] = va.y;
        As[ak4 + 2][am] = va.z;
        As[ak4 + 3][am] = va.w;
        *(float4*)&Bs[bk][bn0] = vb;
        __syncthreads();
#pragma unroll
        for (int k = 0; k < BK; k++) {
            const float4 a4 = *(const float4*)&As[k][tr * 4];
            const float4 b4 = *(const float4*)&Bs[k][tc * 4];
            const float a[4] = {a4.x, a4.y, a4.z, a4.w};
            const float b[4] = {b4.x, b4.y, b4.z, b4.w};
#pragma unroll
            for (int i = 0; i < 4; i++)
#pragma unroll
                for (int j = 0; j < 4; j++)
                    acc[i][j] += a[i] * b[j];
        }
        __syncthreads();
    }
#pragma unroll
    for (int i = 0; i < 4; i++) {
        const int m = bm + tr * 4 + i;
        if (bias) {
            const float4 bv = *(const float4*)&bias[bn + tc * 4];
            acc[i][0] += bv.x; acc[i][1] += bv.y; acc[i][2] += bv.z; acc[i][3] += bv.w;
        }
        if (C_h) {
            __half2 p0 = __floats2half2_rn(acc[i][0], acc[i][1]);
            __half2 p1 = __floats2half2_rn(acc[i][2], acc[i][3]);
            __half2* hp = (__half2*)&C_h[(size_t)m * N + bn + tc * 4];
            hp[0] = p0;
            hp[1] = p1;
        } else {
            float4 o = {acc[i][0], acc[i][1], acc[i][2], acc[i][3]};
            *(float4*)&Cw[(size_t)m * N + bn + tc * 4] = o;
        }
    }
    if (asrc) {
        const int h = blockIdx.x;                  // BN==DHEAD
        const float4 as4 = *(const float4*)&asrc[h * DHEAD + tc * 4];
        const float4 ad4 = *(const float4*)&adst[h * DHEAD + tc * 4];
#pragma unroll
        for (int i = 0; i < 4; i++) {
            float vs = acc[i][0] * as4.x + acc[i][1] * as4.y +
                       acc[i][2] * as4.z + acc[i][3] * as4.w;
            float vd = acc[i][0] * ad4.x + acc[i][1] * ad4.y +
                       acc[i][2] * ad4.z + acc[i][3] * ad4.w;
#pragma unroll
            for (int off = 1; off < 16; off <<= 1) {
                vs += __shfl_xor(vs, off, 64);
                vd += __shfl_xor(vd, off, 64);
            }
            if (tc == 0) {
                const int m = bm + tr * 4 + i;
                fs[h * M + m] = vs;
                fd[h * M + m] = vd;
            }
        }
    }
}

// Fused reduction of W-partials (len1, nz1) and bias-partials (len2, nz2).
__global__ __launch_bounds__(256) void reduce_both(const float* __restrict__ p1,
                                                   float* __restrict__ o1,
                                                   int len1, int nz1,
                                                   const float* __restrict__ p2,
                                                   float* __restrict__ o2,
                                                   int len2, int nz2,
                                                   int blocks1) {
    if ((int)blockIdx.x < blocks1) {
        const int i = blockIdx.x * 256 + threadIdx.x;
        if (i < len1) {
            float s = 0.0f;
            for (int z = 0; z < nz1; z++) s += p1[(size_t)z * len1 + i];
            o1[i] = s;
        }
    } else {
        const int i = (blockIdx.x - blocks1) * 256 + threadIdx.x;
        if (i < len2) {
            float s = 0.0f;
            for (int z = 0; z < nz2; z++) s += p2[(size_t)z * len2 + i];
            o2[i] = s;
        }
    }
}

// ---------------------------------------------------------------------------
// Fused split-K reduce + attention logits for the sub layer.
// ---------------------------------------------------------------------------
__global__ __launch_bounds__(512) void reduce_fsfd(const float* __restrict__ part,
                                                   float* __restrict__ wh,
                                                   const float* __restrict__ asrc,
                                                   const float* __restrict__ adst,
                                                   float* __restrict__ fs,
                                                   float* __restrict__ fd,
                                                   int M, int nz) {
    const int n = blockIdx.x;
    const int tid = threadIdx.x;
    float v = 0.0f;
    for (int z = 0; z < nz; z++)
        v += part[((size_t)z * M + n) * HIDDEN + tid];
    wh[(size_t)n * HIDDEN + tid] = v;
    const int h = tid >> 6;
    const int d = tid & 63;
    float vs = v * asrc[h * DHEAD + d];
    float vd = v * adst[h * DHEAD + d];
#pragma unroll
    for (int off = 32; off >= 1; off >>= 1) {
        vs += __shfl_xor(vs, off, 64);
        vd += __shfl_xor(vd, off, 64);
    }
    if (d == 0) {
        fs[h * M + n] = vs;
        fd[h * M + n] = vd;
    }
}

// ---------------------------------------------------------------------------
// Shared softmax phase for block-per-row agg (used by gat_agg_f).
// ---------------------------------------------------------------------------
__device__ __forceinline__ void gat_softmax(const float* __restrict__ fs,
                                            const float* __restrict__ fd,
                                            const int* snbr, float (*ex)[CAP + 1],
                                            int C, int i, int N, int tid) {
    const int h = tid >> 6;
    const int lane = tid & 63;
    const float fsi = fs[h * N + i];
    const float* __restrict__ fdh = fd + h * N;
    float m = -1e30f;
    for (int k = lane; k < C; k += 64) {
        float e = fsi + fdh[snbr[k]];
        e = e > 0.0f ? e : 0.2f * e;
        ex[h][k] = e;
        m = fmaxf(m, e);
    }
#pragma unroll
    for (int off = 32; off >= 1; off >>= 1) m = fmaxf(m, __shfl_xor(m, off, 64));
    float ssum = 0.0f;
    for (int k = lane; k < C; k += 64) {
        float v = __expf(ex[h][k] - m);
        ex[h][k] = v;
        ssum += v;
    }
#pragma unroll
    for (int off = 32; off >= 1; off >>= 1) ssum += __shfl_xor(ssum, off, 64);
    const float inv = 1.0f / ssum;
    for (int k = lane; k < C; k += 64) ex[h][k] *= inv;
}

// ---------------------------------------------------------------------------
// Node GAT aggregate v5: ONE WAVE PER NODE — zero barriers, no cross-wave
// reduce. Wave w of a block handles node i = blockIdx.x*8 + w.
//  Softmax: lane = head*8 + slot; 8-lane xor-shuffle reduce; alphas in LDS
//  (stride CAP+4 -> <=2-way bank alias, free). Gather: lane owns 8 halves of
//  the row (64 lanes x 16B = 1KB/neighbor, coalesced); 8-deep pipelined loop
//  over ALL C neighbors of the wave's node. fp32 accum, ELU, float4 stores.
// ---------------------------------------------------------------------------
__global__ __launch_bounds__(512) void gat_agg_h(const __half* __restrict__ Wh,
                                                 const float* __restrict__ fs,
                                                 const float* __restrict__ fd,
                                                 const int* __restrict__ cnt,
                                                 const int* __restrict__ nbr,
                                                 float* __restrict__ out, int N) {
    __shared__ int snbr[8][CAP];               // 4 KB
    __shared__ float al[8][NHEADS][CAPP];      // 33 KB
    const int w = threadIdx.x >> 6;            // wave 0..7
    const int lane = threadIdx.x & 63;
    const int i = blockIdx.x * 8 + w;
    int C = cnt[i];
    C = C < CAP ? C : CAP;
    for (int k = lane; k < C; k += 64) snbr[w][k] = nbr[(i << 7) + k];
    // --- in-wave softmax: lane = h*8 + s ---
    const int h = lane >> 3;
    const int s = lane & 7;
    const float fsi = fs[h * N + i];
    const float* __restrict__ fdh = fd + h * N;
    float m = -1e30f;
    for (int k = s; k < C; k += 8) {
        float e = fsi + fdh[snbr[w][k]];
        e = e > 0.0f ? e : 0.2f * e;
        al[w][h][k] = e;
        m = fmaxf(m, e);
    }
    m = fmaxf(m, __shfl_xor(m, 1, 64));
    m = fmaxf(m, __shfl_xor(m, 2, 64));
    m = fmaxf(m, __shfl_xor(m, 4, 64));
    float ssum = 0.0f;
    for (int k = s; k < C; k += 8) {
        float v = __expf(al[w][h][k] - m);
        al[w][h][k] = v;
        ssum += v;
    }
    ssum += __shfl_xor(ssum, 1, 64);
    ssum += __shfl_xor(ssum, 2, 64);
    ssum += __shfl_xor(ssum, 4, 64);
    const float inv = 1.0f / ssum;             // self-loop: C>=1
    for (int k = s; k < C; k += 8) al[w][h][k] *= inv;
    // --- gather: lane owns halves [8*lane, 8*lane+8) of the output row ---
    float acc[8] = {};
    int k = 0;
    for (; k + 8 <= C; k += 8) {
        h8 ww[8];
        float aa[8];
#pragma unroll
        for (int u = 0; u < 8; u++) {
            ww[u] = *(const h8*)&Wh[(size_t)snbr[w][k + u] * HIDDEN + 8 * lane];
            aa[u] = al[w][h][k + u];
        }
#pragma unroll
        for (int u = 0; u < 8; u++) {
            float2 f;
            f = __half22float2(ww[u].a); acc[0] += aa[u] * f.x; acc[1] += aa[u] * f.y;
            f = __half22float2(ww[u].b); acc[2] += aa[u] * f.x; acc[3] += aa[u] * f.y;
            f = __half22float2(ww[u].c); acc[4] += aa[u] * f.x; acc[5] += aa[u] * f.y;
            f = __half22float2(ww[u].d); acc[6] += aa[u] * f.x; acc[7] += aa[u] * f.y;
        }
    }
    for (; k < C; k++) {
        const h8 w0 = *(const h8*)&Wh[(size_t)snbr[w][k] * HIDDEN + 8 * lane];
        const float a0 = al[w][h][k];
        float2 f;
        f = __half22float2(w0.a); acc[0] += a0 * f.x; acc[1] += a0 * f.y;
        f = __half22float2(w0.b); acc[2] += a0 * f.x; acc[3] += a0 * f.y;
        f = __half22float2(w0.c); acc[4] += a0 * f.x; acc[5] += a0 * f.y;
        f = __half22float2(w0.d); acc[6] += a0 * f.x; acc[7] += a0 * f.y;
    }
#pragma unroll
    for (int e = 0; e < 8; e++)
        acc[e] = acc[e] > 0.0f ? acc[e] : __expf(acc[e]) - 1.0f;
    float4 o0 = {acc[0], acc[1], acc[2], acc[3]};
    float4 o1 = {acc[4], acc[5], acc[6], acc[7]};
    float4* op = (float4*)&out[(size_t)i * HIDDEN + 8 * lane];
    op[0] = o0;
    op[1] = o1;
}

// ---------------------------------------------------------------------------
// Sub GAT aggregate (R11-proven): fp32 gather, block per row, 4-deep ILP.
// ---------------------------------------------------------------------------
__global__ __launch_bounds__(512) void gat_agg_f(const float* __restrict__ Wh,
                                                 const float* __restrict__ fs,
                                                 const float* __restrict__ fd,
                                                 const int* __restrict__ cnt,
                                                 const int* __restrict__ nbr,
                                                 float* __restrict__ out, int N) {
    __shared__ int snbr[CAP];
    __shared__ float ex[NHEADS][CAP + 1];
    __shared__ float sacc[ROWG][HIDDEN];
    const int i = blockIdx.x;
    const int tid = threadIdx.x;
    int C = cnt[i];
    C = C < CAP ? C : CAP;
    for (int k = tid; k < C; k += 512) snbr[k] = nbr[(i << 7) + k];
    __syncthreads();
    gat_softmax(fs, fd, snbr, ex, C, i, N, tid);
    __syncthreads();
    const int g = tid >> 7;
    const int t = tid & 127;
    const int hh = t >> 4;
    float4 acc = {0.f, 0.f, 0.f, 0.f};
    int k = g;
    for (; k + 3 * ROWG < C; k += 4 * ROWG) {
        const int j0 = snbr[k];
        const int j1 = snbr[k + ROWG];
        const int j2 = snbr[k + 2 * ROWG];
        const int j3 = snbr[k + 3 * ROWG];
        const float a0 = ex[hh][k];
        const float a1 = ex[hh][k + ROWG];
        const float a2 = ex[hh][k + 2 * ROWG];
        const float a3 = ex[hh][k + 3 * ROWG];
        const float4 w0 = *(const float4*)&Wh[(size_t)j0 * HIDDEN + 4 * t];
        const float4 w1 = *(const float4*)&Wh[(size_t)j1 * HIDDEN + 4 * t];
        const float4 w2 = *(const float4*)&Wh[(size_t)j2 * HIDDEN + 4 * t];
        const float4 w3 = *(const float4*)&Wh[(size_t)j3 * HIDDEN + 4 * t];
        acc.x += a0 * w0.x + a1 * w1.x + a2 * w2.x + a3 * w3.x;
        acc.y += a0 * w0.y + a1 * w1.y + a2 * w2.y + a3 * w3.y;
        acc.z += a0 * w0.z + a1 * w1.z + a2 * w2.z + a3 * w3.z;
        acc.w += a0 * w0.w + a1 * w1.w + a2 * w2.w + a3 * w3.w;
    }
    for (; k < C; k += ROWG) {
        const int j0 = snbr[k];
        const float a0 = ex[hh][k];
        const float4 w0 = *(const float4*)&Wh[(size_t)j0 * HIDDEN + 4 * t];
        acc.x += a0 * w0.x; acc.y += a0 * w0.y;
        acc.z += a0 * w0.z; acc.w += a0 * w0.w;
    }
    *(float4*)&sacc[g][4 * t] = acc;
    __syncthreads();
    if (g == 0) {
        float4 r = acc;
#pragma unroll
        for (int gg = 1; gg < ROWG; gg++) {
            const float4 o = *(const float4*)&sacc[gg][4 * t];
            r.x += o.x; r.y += o.y; r.z += o.z; r.w += o.w;
        }
        r.x = r.x > 0.0f ? r.x : __expf(r.x) - 1.0f;
        r.y = r.y > 0.0f ? r.y : __expf(r.y) - 1.0f;
        r.z = r.z > 0.0f ? r.z : __expf(r.z) - 1.0f;
        r.w = r.w > 0.0f ? r.w : __expf(r.w) - 1.0f;
        *(float4*)&out[(size_t)i * HIDDEN + 4 * t] = r;
    }
}

// ---------------------------------------------------------------------------
// Segment-mean pooling. seg_ids sorted. One block per substation.
// ---------------------------------------------------------------------------
__global__ __launch_bounds__(512) void pool_kernel(const float* __restrict__ hin,
                                                   const int* __restrict__ seg,
                                                   float* __restrict__ sout) {
    const int s = blockIdx.x;
    const int d = threadIdx.x;
    int lo = 0, hi = N_NODES;
    while (lo < hi) { int mid = (lo + hi) >> 1; if (seg[mid] < s) lo = mid + 1; else hi = mid; }
    const int start = lo;
    hi = N_NODES;
    while (lo < hi) { int mid = (lo + hi) >> 1; if (seg[mid] < s + 1) lo = mid + 1; else hi = mid; }
    const int end = lo;
    float acc = 0.0f;
    for (int r = start; r < end; r++) acc += hin[(size_t)r * HIDDEN + d];
    const int c = end - start;
    sout[(size_t)s * HIDDEN + d] = acc / (c > 0 ? (float)c : 1.0f);
}

// ---------------------------------------------------------------------------
extern "C" void kernel_launch(void* const* d_in, const int* in_sizes, int n_in,
                              void* d_out, int out_size, void* d_ws, size_t ws_size,
                              hipStream_t stream) {
    const float* x        = (const float*)d_in[0];
    const float* adj_node = (const float*)d_in[1];
    const float* adj_sub  = (const float*)d_in[2];
    const int*   seg_ids  = (const int*)d_in[3];
    const float* lin_w    = (const float*)d_in[4];
    const float* lin_b    = (const float*)d_in[5];
    // _stacked_gats bug: every layer reads the ORIGINAL h; only the LAST
    // layer's output survives. Use layer index 1 only.
    const float* node_W1    = (const float*)d_in[6]  + HIDDEN * HIDDEN;
    const float* node_asrc1 = (const float*)d_in[7]  + NHEADS * DHEAD;
    const float* node_adst1 = (const float*)d_in[8]  + NHEADS * DHEAD;
    const float* sub_W1     = (const float*)d_in[9]  + HIDDEN * HIDDEN;
    const float* sub_asrc1  = (const float*)d_in[10] + NHEADS * DHEAD;
    const float* sub_adst1  = (const float*)d_in[11] + NHEADS * DHEAD;
    float* out = (float*)d_out;

    char* ws = (char*)d_ws;
    float* bufA  = (float*)(ws);                              // 8 MB
    float* bufB  = (float*)(ws + (size_t)8 * 1024 * 1024);    // 8 MB
    float* fs_n  = (float*)(ws + (size_t)16 * 1024 * 1024);
    float* fd_n  = fs_n + NHEADS * N_NODES;
    float* fs_s  = fd_n + NHEADS * N_NODES;
    float* fd_s  = fs_s + NHEADS * N_SUBS;
    int*   cnt_n = (int*)(fd_s + NHEADS * N_SUBS);
    int*   cnt_s = cnt_n + N_NODES;
    int*   nbr_n = cnt_s + N_SUBS;                            // 2 MB
    int*   nbr_s = nbr_n + N_NODES * CAP;                     // 512 KB

    // bufB overlays: phase-1 GEMM scratch -> gatom -> Spart
    float*  Wpart = bufB;                                     // 16*128*512 (4 MB)
    float*  Wfuse = bufB + 16 * NFEAT * HIDDEN;               // 256 KB
    float*  bpart = Wfuse + NFEAT * HIDDEN;                   // 32 KB
    float*  bias2 = bpart + 16 * HIDDEN;                      // 2 KB
    float*  gatom = bufB;                                     // 4096*512 (after gemm3)
    float*  Spart = bufB;                                     // 4*1024*512 (after pool)
    // bufA overlays: wh_n(fp16) -> sp -> wh_s
    __half* wh_n  = (__half*)bufA;                            // 4096*512 fp16 (4 MB)
    float*  sp    = bufA;                                     // 1024*512 (wh_n dead)
    float*  wh_s  = bufA + (size_t)N_SUBS * HIDDEN;           // 1024*512

    // 1. PHASE 1: edge extraction + Wpart split-K GEMM + bias slab
    phase1<<<NB_EXTRACT + NB_GEMM, 256, 0, stream>>>(
        adj_node, adj_sub, cnt_n, nbr_n, cnt_s, nbr_s,
        lin_w, node_W1, lin_b, Wpart, bpart);
    // 2. reduce W partials + bias partials -> Wfuse, bias2
    reduce_both<<<NFEAT * HIDDEN / 256 + 2, 256, 0, stream>>>(
        Wpart, Wfuse, NFEAT * HIDDEN, 16, bpart, bias2, HIDDEN, 16,
        NFEAT * HIDDEN / 256);
    // 3. wh_n(fp16) = x @ Wfuse + bias2, fused fs/fd epilogue
    gemm_f32<<<dim3(HIDDEN / BN, N_NODES / BM, 1), 256, 0, stream>>>(
        x, Wfuse, bias2, nullptr, N_NODES, HIDDEN, NFEAT, NFEAT,
        node_asrc1, node_adst1, fs_n, fd_n, wh_n);
    // 4. node GAT aggregate (wave-per-node, barrier-free) -> gatom
    gat_agg_h<<<N_NODES / 8, 512, 0, stream>>>(wh_n, fs_n, fd_n, cnt_n, nbr_n,
                                               gatom, N_NODES);
    // 5. segment-mean pool -> sp (bufA; wh_n dead)
    pool_kernel<<<N_SUBS, 512, 0, stream>>>(gatom, seg_ids, sp);
    // 6. wh_s partials = sp @ sub_W1 (split-K=4)
    gemm_f32<<<dim3(HIDDEN / BN, N_SUBS / BM, 4), 256, 0, stream>>>(
        sp, sub_W1, nullptr, Spart, N_SUBS, HIDDEN, HIDDEN, HIDDEN / 4,
        nullptr, nullptr, nullptr, nullptr, nullptr);
    // 7. fused reduce + sub attention logits
    reduce_fsfd<<<N_SUBS, 512, 0, stream>>>(Spart, wh_s, sub_asrc1, sub_adst1,
                                            fs_s, fd_s, N_SUBS, 4);
    // 8. sub GAT aggregate (fp32) -> final output
    gat_agg_f<<<N_SUBS, 512, 0, stream>>>(wh_s, fs_s, fd_s, cnt_s, nbr_s,
                                          out, N_SUBS);
}